// Round 3
// baseline (2544.672 us; speedup 1.0000x reference)
//
#include <hip/hip_runtime.h>
#include <cstddef>

#define DEV_INLINE __device__ __forceinline__

constexpr int U_N = 100000;
constexpr int I_N = 50000;
constexpr int R_N = 5;
constexpr int E_N = 100000;
constexpr int K_N = 4;
constexpr int D_N = 16;
constexpr int RD_N = 64;
constexpr int OUT_N = 64;
constexpr int KF_N = 2;
constexpr float INV_TAU = 2.0f;   // 1/TAU, TAU=0.5

constexpr int NE_TOT = R_N * E_N;        // 500000 edges
constexpr int NNODE  = U_N + I_N;        // 150000 nodes (users then items)
constexpr int NB_ALLOC = (NNODE + 255) / 256;  // 586 alloc blocks

// workspace layout in 4-byte elements.
// [cnt | norm | gcnt] are contiguous and zeroed by ONE memset (300001 ints).
constexpr size_t OFS_CNT    = 0;            // NNODE ints
constexpr size_t OFS_NORM   = 150000;       // NNODE floats
constexpr size_t OFS_GCNT   = 300000;       // 1 int (global segment cursor)
constexpr size_t OFS_OFF    = 300004;       // NNODE ints
constexpr size_t OFS_CURSOR = 450004;       // NNODE ints
constexpr size_t OFS_LIST   = 600004;       // 2*NE_TOT ints
constexpr size_t OFS_EAD    = 1600004;      // NE_TOT floats
constexpr size_t OFS_MFWD   = 2100004;      // NE_TOT*16 floats (elem ofs %4==0 -> 16B aligned)
constexpr size_t OFS_MREV   = 10100004;     // NE_TOT*16 floats (elem ofs %4==0)
// total used = 18,100,004 elems = 72.4 MB

DEV_INLINE float dot4(float4 a, float4 b) { return a.x*b.x + a.y*b.y + a.z*b.z + a.w*b.w; }
DEV_INLINE void fma4(float4& a, float s, float4 w) { a.x += s*w.x; a.y += s*w.y; a.z += s*w.z; a.w += s*w.w; }
DEV_INLINE float comp(float4 v, int i) { return i == 0 ? v.x : i == 1 ? v.y : i == 2 ? v.z : v.w; }

// ---------------------------------------------------------------------------
// Phase 1 (FUSED, EDGE_BLK=4): per-edge ead + counts/norm atomics, then
// register-blocked message GEMM: each quad owns 4 consecutive edges, lane l
// owns output columns [4l,4l+4). Every LDS weight read is amortized over the
// 4 edges (ds_read instr/edge: 10 -> 2.5). launch_bounds(256,4) lets the
// compiler use up to ~128 VGPRs for accumulators + batched gather loads.
// grid = (ceil(E/256), R)
// ---------------------------------------------------------------------------
__global__ __launch_bounds__(256, 4) void phase1_kernel(
    const float* __restrict__ user_h, const float* __restrict__ item_h,
    const float* __restrict__ user_hsum, const float* __restrict__ item_hsum,
    const float* __restrict__ review_feat, const float* __restrict__ prototypes,
    const float* __restrict__ eta,
    const float* __restrict__ node_w_fwd, const float* __restrict__ node_w_rev,
    const float* __restrict__ review_w_fwd, const float* __restrict__ review_w_rev,
    const int* __restrict__ rows, const int* __restrict__ cols,
    float* __restrict__ ead_ws,
    float* __restrict__ m_fwd, float* __restrict__ m_rev,
    int* __restrict__ cnt, float* __restrict__ norm)
{
    __shared__ __align__(16) float proto_s[K_N * RD_N];   // 256 floats
    __shared__ __align__(16) float nwf_s[D_N * D_N];      // 256
    __shared__ __align__(16) float nwr_s[D_N * D_N];      // 256
    __shared__ __align__(16) float rwf_s[RD_N * D_N];     // 1024
    __shared__ __align__(16) float rwr_s[RD_N * D_N];     // 1024
    const int tid = threadIdx.x;
    const int r = blockIdx.y;
    proto_s[tid] = prototypes[tid];
    nwf_s[tid] = node_w_fwd[r * D_N * D_N + tid];
    nwr_s[tid] = node_w_rev[r * D_N * D_N + tid];
#pragma unroll
    for (int q = 0; q < 4; ++q) {
        rwf_s[q*256 + tid] = review_w_fwd[r * RD_N * D_N + q*256 + tid];
        rwr_s[q*256 + tid] = review_w_rev[r * RD_N * D_N + q*256 + tid];
    }
    __syncthreads();

    const int qid = tid >> 2;                    // quad id 0..63
    const int l = tid & 3;                       // lane-in-quad
    const int e0 = blockIdx.x * 256 + (qid << 2);
    if (e0 >= E_N) return;

    int rowv[4], colv[4];

    // ---------------- Phase A: ead + atomics, per edge ----------------
#pragma unroll
    for (int es = 0; es < 4; ++es) {
        const int e = min(e0 + es, E_N - 1);     // clamp; stores guarded below
        const size_t re = (size_t)r * E_N + e;
        const int row = rows[re];
        const int col = cols[re];
        rowv[es] = row;
        colv[es] = col;

        // cosine sim: each lane one float4 of the 16-vector, quad reduce
        const float4* uh4 = (const float4*)(user_h + ((size_t)r * U_N + row) * D_N);
        const float4* ih4 = (const float4*)(item_h + ((size_t)r * I_N + col) * D_N);
        const float4 a = uh4[l], b = ih4[l];
        float du = dot4(a, a), di = dot4(b, b), dui = dot4(a, b);
        du  += __shfl_xor(du, 1);  du  += __shfl_xor(du, 2);
        di  += __shfl_xor(di, 1);  di  += __shfl_xor(di, 2);
        dui += __shfl_xor(dui, 1); dui += __shfl_xor(dui, 2);
        const float sim_k = dui / sqrtf(du * di) * INV_TAU;

        // sim_all: lane l handles k=l (64B chunk of the 256B row)
        const float4* us4 = (const float4*)(user_hsum + ((size_t)r * U_N + row) * (K_N * D_N)) + l * 4;
        const float4* is4 = (const float4*)(item_hsum + ((size_t)r * I_N + col) * (K_N * D_N)) + l * 4;
        float s = 0.f;
#pragma unroll
        for (int q = 0; q < 4; ++q) s += dot4(us4[q], is4[q]);
        float ssum = expf(s * INV_TAU);
        ssum += __shfl_xor(ssum, 1); ssum += __shfl_xor(ssum, 2);
        const float exp_sim = expf(sim_k) / ssum;

        // ad: lane l handles k=l (256B chunk of the 1KB review row)
        const float4* rf4 = (const float4*)(review_feat + re * (size_t)(K_N * RD_N)) + l * 16;
        const float4* pr4 = (const float4*)proto_s + l * 16;
        float t = 0.f;
#pragma unroll
        for (int q = 0; q < 16; ++q) t += dot4(rf4[q], pr4[q]);
        t *= INV_TAU;
        float adsum = expf(t);
        adsum += __shfl_xor(adsum, 1); adsum += __shfl_xor(adsum, 2);
        const float adk = __shfl(t, KF_N, 4);
        const float ead_rev = expf(adk) / adsum;

        const float g = 1.0f / (1.0f + expf(-eta[re]));
        const float ead = g * ead_rev + (1.0f - g) * exp_sim;
        if (l == 0 && e0 + es < E_N) {
            ead_ws[re] = ead;
            atomicAdd(cnt + row, 1);
            atomicAdd(cnt + U_N + col, 1);
            atomicAdd(norm + row, ead);
            atomicAdd(norm + U_N + col, ead);
        }
    }

    // ---------------- Phase B: register-blocked messages ----------------
    float4 mf[4], mr[4];
#pragma unroll
    for (int es = 0; es < 4; ++es) {
        mf[es] = make_float4(0.f, 0.f, 0.f, 0.f);
        mr[es] = make_float4(0.f, 0.f, 0.f, 0.f);
    }

    const float4* nf4 = (const float4*)nwf_s;
    const float4* nr4 = (const float4*)nwr_s;
#pragma unroll
    for (int jq = 0; jq < 4; ++jq) {
        float4 uv[4], iv[4];
#pragma unroll
        for (int es = 0; es < 4; ++es) {
            uv[es] = ((const float4*)(user_h + ((size_t)r * U_N + rowv[es]) * D_N))[jq];
            iv[es] = ((const float4*)(item_h + ((size_t)r * I_N + colv[es]) * D_N))[jq];
        }
#pragma unroll
        for (int jj = 0; jj < 4; ++jj) {
            const int j = jq*4 + jj;
            const float4 wf = nf4[j*4 + l];      // one LDS read serves 4 edges
            const float4 wr = nr4[j*4 + l];
#pragma unroll
            for (int es = 0; es < 4; ++es) {
                fma4(mf[es], comp(uv[es], jj), wf);
                fma4(mr[es], comp(iv[es], jj), wr);
            }
        }
    }

    const float4* rf4w = (const float4*)rwf_s;
    const float4* rr4w = (const float4*)rwr_s;
    const float4* rfk[4];
#pragma unroll
    for (int es = 0; es < 4; ++es) {
        const int e = min(e0 + es, E_N - 1);
        rfk[es] = (const float4*)(review_feat
                    + ((size_t)r * E_N + e) * (size_t)(K_N * RD_N) + KF_N * RD_N);
    }
#pragma unroll
    for (int jq = 0; jq < 16; ++jq) {
        float4 v[4];
#pragma unroll
        for (int es = 0; es < 4; ++es) v[es] = rfk[es][jq];   // L1/L2-hot (ad loop)
#pragma unroll
        for (int jj = 0; jj < 4; ++jj) {
            const int j = jq*4 + jj;
            const float4 wf = rf4w[j*4 + l];     // one LDS read serves 4 edges
            const float4 wr = rr4w[j*4 + l];
#pragma unroll
            for (int es = 0; es < 4; ++es) {
                fma4(mf[es], comp(v[es], jj), wf);
                fma4(mr[es], comp(v[es], jj), wr);
            }
        }
    }

#pragma unroll
    for (int es = 0; es < 4; ++es) {
        if (e0 + es < E_N) {
            const size_t re = (size_t)r * E_N + (e0 + es);
            *((float4*)(m_fwd + re * (size_t)D_N) + l) = mf[es];
            *((float4*)(m_rev + re * (size_t)D_N) + l) = mr[es];
        }
    }
}

// ---------------------------------------------------------------------------
// Segment alloc: replaces the 3-kernel prefix scan. CSR segments only need to
// be DISJOINT, not node-ordered: each block claims a contiguous region via one
// atomicAdd on a global cursor; wave shuffle-scan assigns per-node offsets.
// Consumers use [off[n], off[n]+cnt[n]).
// ---------------------------------------------------------------------------
__global__ __launch_bounds__(256) void alloc_kernel(
    const int* __restrict__ cnt, int* __restrict__ off, int* __restrict__ cursor,
    int* __restrict__ gcnt)
{
    __shared__ int s_wsum[4];
    const int tid = threadIdx.x;
    const int lane = tid & 63;
    const int wid = tid >> 6;
    const int n = blockIdx.x * 256 + tid;
    const int v = (n < NNODE) ? cnt[n] : 0;
    int incl = v;
#pragma unroll
    for (int d = 1; d < 64; d <<= 1) {
        const int x = __shfl_up(incl, d);
        if (lane >= d) incl += x;
    }
    if (lane == 63) s_wsum[wid] = incl;
    __syncthreads();
    if (tid == 0) {
        const int t0 = s_wsum[0], t1 = s_wsum[1], t2 = s_wsum[2], t3 = s_wsum[3];
        const int base = atomicAdd(gcnt, t0 + t1 + t2 + t3);
        s_wsum[0] = base;
        s_wsum[1] = base + t0;
        s_wsum[2] = base + t0 + t1;
        s_wsum[3] = base + t0 + t1 + t2;
    }
    __syncthreads();
    if (n < NNODE) {
        const int o = s_wsum[wid] + incl - v;   // exclusive within wave
        off[n] = o;
        cursor[n] = o;
    }
}

// ---------------------------------------------------------------------------
// Fill + wscale (FUSED): scatter edge ids into CSR list AND write the final
// per-edge weight w = ead/sqrt(norm_u*norm_i) straight into the int_dist
// output region (which doubles as gatherfc's scale array).
// ---------------------------------------------------------------------------
__global__ __launch_bounds__(256) void fillw_kernel(
    const int* __restrict__ rows, const int* __restrict__ cols,
    const float* __restrict__ ead, const float* __restrict__ norm,
    int* __restrict__ cursor, int* __restrict__ list,
    float* __restrict__ w_out)
{
    const int idx = blockIdx.x * 256 + threadIdx.x;
    if (idx >= NE_TOT) return;
    const int row = rows[idx];
    const int col = cols[idx];
    const int p = atomicAdd(cursor + row, 1);
    list[p] = idx;
    const int q = atomicAdd(cursor + U_N + col, 1);
    list[q] = idx;
    w_out[idx] = ead[idx] / sqrtf(norm[row] * norm[U_N + col]);
}

// ---------------------------------------------------------------------------
// Gather + FC (FUSED): 4 lanes per node. Each lane sums one float4 slice of
// w * m over incident edges, applies leaky-ReLU, then the quad broadcasts the
// 16-vector via width-4 shuffles and each lane computes 16 of 64 FC outputs,
// writing to d_out directly. Users consume m_rev; items consume m_fwd.
// Segment = [off[n], off[n]+cnt[n]).
// ---------------------------------------------------------------------------
__global__ __launch_bounds__(256) void gatherfc_kernel(
    const int* __restrict__ off, const int* __restrict__ cnt,
    const int* __restrict__ list,
    const float* __restrict__ m_fwd, const float* __restrict__ m_rev,
    const float* __restrict__ w_edge,
    const float* __restrict__ ufc_w, const float* __restrict__ ufc_b,
    const float* __restrict__ ifc_w, const float* __restrict__ ifc_b,
    float* __restrict__ out)
{
    __shared__ __align__(16) float uw_s[D_N * OUT_N];   // 1024
    __shared__ __align__(16) float iw_s[D_N * OUT_N];   // 1024
    __shared__ __align__(16) float ub_s[OUT_N];
    __shared__ __align__(16) float ib_s[OUT_N];
    const int tid = threadIdx.x;
#pragma unroll
    for (int q = 0; q < 4; ++q) {
        uw_s[q*256 + tid] = ufc_w[q*256 + tid];
        iw_s[q*256 + tid] = ifc_w[q*256 + tid];
    }
    if (tid < OUT_N) ub_s[tid] = ufc_b[tid];
    else if (tid < 2*OUT_N) ib_s[tid - OUT_N] = ifc_b[tid - OUT_N];
    __syncthreads();

    const int gid = blockIdx.x * 256 + tid;
    const int n = gid >> 2;
    const int l = gid & 3;
    if (n >= NNODE) return;
    const int p0 = off[n];
    const int p1 = p0 + cnt[n];
    const bool isU = (n < U_N);
    const float* __restrict__ src = isU ? m_rev : m_fwd;
    float4 acc = make_float4(0.f, 0.f, 0.f, 0.f);
    for (int p = p0; p < p1; ++p) {
        const int e = list[p];
        const float w = w_edge[e];                      // 4B, L2-resident
        const float4 v = *((const float4*)(src + (size_t)e * D_N) + l);
        fma4(acc, w, v);
    }
    // leaky ReLU on this lane's 4 features
    acc.x = (acc.x >= 0.f) ? acc.x : 0.1f * acc.x;
    acc.y = (acc.y >= 0.f) ? acc.y : 0.1f * acc.y;
    acc.z = (acc.z >= 0.f) ? acc.z : 0.1f * acc.z;
    acc.w = (acc.w >= 0.f) ? acc.w : 0.1f * acc.w;

    const float* __restrict__ W = isU ? uw_s : iw_s;
    const float* __restrict__ B = isU ? ub_s : ib_s;
    float* __restrict__ dst = isU ? (out + (size_t)n * OUT_N)
                                  : (out + (size_t)U_N * OUT_N + (size_t)(n - U_N) * OUT_N);

    // lane l computes outputs [16l, 16l+16)
    float4 s0 = *(const float4*)(B + 16*l + 0);
    float4 s1 = *(const float4*)(B + 16*l + 4);
    float4 s2 = *(const float4*)(B + 16*l + 8);
    float4 s3 = *(const float4*)(B + 16*l + 12);
#pragma unroll
    for (int sl = 0; sl < 4; ++sl) {
        float4 fv;
        fv.x = __shfl(acc.x, sl, 4);
        fv.y = __shfl(acc.y, sl, 4);
        fv.z = __shfl(acc.z, sl, 4);
        fv.w = __shfl(acc.w, sl, 4);
#pragma unroll
        for (int jj = 0; jj < 4; ++jj) {
            const int d = sl*4 + jj;
            const float x = comp(fv, jj);
            fma4(s0, x, *(const float4*)(W + d*OUT_N + 16*l + 0));
            fma4(s1, x, *(const float4*)(W + d*OUT_N + 16*l + 4));
            fma4(s2, x, *(const float4*)(W + d*OUT_N + 16*l + 8));
            fma4(s3, x, *(const float4*)(W + d*OUT_N + 16*l + 12));
        }
    }
    ((float4*)dst)[4*l + 0] = s0;
    ((float4*)dst)[4*l + 1] = s1;
    ((float4*)dst)[4*l + 2] = s2;
    ((float4*)dst)[4*l + 3] = s3;
}

// ---------------------------------------------------------------------------
extern "C" void kernel_launch(void* const* d_in, const int* in_sizes, int n_in,
                              void* d_out, int out_size, void* d_ws, size_t ws_size,
                              hipStream_t stream)
{
    const float* user_h       = (const float*)d_in[0];
    const float* item_h       = (const float*)d_in[1];
    const float* user_hsum    = (const float*)d_in[2];
    const float* item_hsum    = (const float*)d_in[3];
    const float* review_feat  = (const float*)d_in[4];
    const float* prototypes   = (const float*)d_in[5];
    const float* eta          = (const float*)d_in[6];
    const float* node_w_fwd   = (const float*)d_in[7];
    const float* node_w_rev   = (const float*)d_in[8];
    const float* review_w_fwd = (const float*)d_in[9];
    const float* review_w_rev = (const float*)d_in[10];
    const float* ufc_w        = (const float*)d_in[11];
    const float* ufc_b        = (const float*)d_in[12];
    const float* ifc_w        = (const float*)d_in[13];
    const float* ifc_b        = (const float*)d_in[14];
    const int*   rows         = (const int*)d_in[15];
    const int*   cols         = (const int*)d_in[16];

    int*   wsi = (int*)d_ws;
    float* wsf = (float*)d_ws;
    float* out = (float*)d_out;

    int*   cnt    = wsi + OFS_CNT;
    float* norm   = wsf + OFS_NORM;
    int*   gcnt   = wsi + OFS_GCNT;
    int*   off    = wsi + OFS_OFF;
    int*   cursor = wsi + OFS_CURSOR;
    int*   list   = wsi + OFS_LIST;
    float* ead    = wsf + OFS_EAD;
    float* m_fwd  = wsf + OFS_MFWD;
    float* m_rev  = wsf + OFS_MREV;

    // zero cnt + norm + gcnt in one shot (contiguous, 300001 ints)
    hipMemsetAsync(wsi, 0, (2 * NNODE + 1) * sizeof(int), stream);

    const dim3 blk(256);
    const dim3 g_e((NE_TOT + 255) / 256);

    phase1_kernel<<<dim3((E_N + 255) / 256, R_N), blk, 0, stream>>>(
        user_h, item_h, user_hsum, item_hsum, review_feat, prototypes, eta,
        node_w_fwd, node_w_rev, review_w_fwd, review_w_rev,
        rows, cols, ead, m_fwd, m_rev, cnt, norm);

    alloc_kernel<<<dim3(NB_ALLOC), blk, 0, stream>>>(cnt, off, cursor, gcnt);

    float* int_dist_out = out + (size_t)U_N * OUT_N + (size_t)I_N * OUT_N;
    fillw_kernel<<<g_e, blk, 0, stream>>>(rows, cols, ead, norm, cursor, list,
                                          int_dist_out);

    gatherfc_kernel<<<dim3((NNODE * 4 + 255) / 256), blk, 0, stream>>>(
        off, cnt, list, m_fwd, m_rev, int_dist_out,
        ufc_w, ufc_b, ifc_w, ifc_b, out);
}

// Round 4
// 953.285 us; speedup vs baseline: 2.6694x; 2.6694x over previous
//
#include <hip/hip_runtime.h>
#include <cstddef>

#define DEV_INLINE __device__ __forceinline__

constexpr int U_N = 100000;
constexpr int I_N = 50000;
constexpr int R_N = 5;
constexpr int E_N = 100000;
constexpr int K_N = 4;
constexpr int D_N = 16;
constexpr int RD_N = 64;
constexpr int OUT_N = 64;
constexpr int KF_N = 2;   // used as literal t2 below (k=2 chunk saved in sv0..sv3)
constexpr float INV_TAU = 2.0f;   // 1/TAU, TAU=0.5

constexpr int NE_TOT = R_N * E_N;        // 500000 edges
constexpr int NNODE  = U_N + I_N;        // 150000 nodes (users then items)
constexpr int NB_ALLOC = (NNODE + 255) / 256;  // 586 alloc blocks

// workspace layout in 4-byte elements.
// [cnt | norm | gcnt] are contiguous and zeroed by ONE memset (300001 ints).
constexpr size_t OFS_CNT    = 0;            // NNODE ints
constexpr size_t OFS_NORM   = 150000;       // NNODE floats
constexpr size_t OFS_GCNT   = 300000;       // 1 int (global segment cursor)
constexpr size_t OFS_OFF    = 300004;       // NNODE ints
constexpr size_t OFS_CURSOR = 450004;       // NNODE ints
constexpr size_t OFS_LIST   = 600004;       // 2*NE_TOT ints
constexpr size_t OFS_EAD    = 1600004;      // NE_TOT floats
constexpr size_t OFS_MFWD   = 2100004;      // NE_TOT*16 floats (elem ofs %4==0 -> 16B aligned)
constexpr size_t OFS_MREV   = 10100004;     // NE_TOT*16 floats (elem ofs %4==0)
// total used = 18,100,004 elems = 72.4 MB

DEV_INLINE float dot4(float4 a, float4 b) { return a.x*b.x + a.y*b.y + a.z*b.z + a.w*b.w; }
DEV_INLINE void fma4(float4& a, float s, float4 w) { a.x += s*w.x; a.y += s*w.y; a.z += s*w.z; a.w += s*w.w; }
DEV_INLINE float comp(float4 v, int i) { return i == 0 ? v.x : i == 1 ? v.y : i == 2 ? v.z : v.w; }

// ---------------------------------------------------------------------------
// Phase 1 (FUSED, one edge per quad — R2 structure): ead + counts/norm
// atomics + unscaled messages. Changes vs R2:
//  * review_feat / hsum reads remapped so the quad's 4 lanes cover each 64B
//    line contiguously (per-k partials + quad reduces) -> ~3x fewer cache-line
//    touches per edge.
//  * Phase B performs ZERO global loads: u/i rows come from shuffling the
//    cosine-step registers (a,b); the rf_k chunk comes from shuffling the 4
//    float4s (sv0..sv3) saved during the ad loop.
// grid = (ceil(E*4/256), R)
// ---------------------------------------------------------------------------
__global__ __launch_bounds__(256) void phase1_kernel(
    const float* __restrict__ user_h, const float* __restrict__ item_h,
    const float* __restrict__ user_hsum, const float* __restrict__ item_hsum,
    const float* __restrict__ review_feat, const float* __restrict__ prototypes,
    const float* __restrict__ eta,
    const float* __restrict__ node_w_fwd, const float* __restrict__ node_w_rev,
    const float* __restrict__ review_w_fwd, const float* __restrict__ review_w_rev,
    const int* __restrict__ rows, const int* __restrict__ cols,
    float* __restrict__ ead_ws,
    float* __restrict__ m_fwd, float* __restrict__ m_rev,
    int* __restrict__ cnt, float* __restrict__ norm)
{
    __shared__ __align__(16) float proto_s[K_N * RD_N];   // 256 floats
    __shared__ __align__(16) float nwf_s[D_N * D_N];      // 256
    __shared__ __align__(16) float nwr_s[D_N * D_N];      // 256
    __shared__ __align__(16) float rwf_s[RD_N * D_N];     // 1024
    __shared__ __align__(16) float rwr_s[RD_N * D_N];     // 1024
    const int tid = threadIdx.x;
    const int r = blockIdx.y;
    proto_s[tid] = prototypes[tid];
    nwf_s[tid] = node_w_fwd[r * D_N * D_N + tid];
    nwr_s[tid] = node_w_rev[r * D_N * D_N + tid];
#pragma unroll
    for (int q = 0; q < 4; ++q) {
        rwf_s[q*256 + tid] = review_w_fwd[r * RD_N * D_N + q*256 + tid];
        rwr_s[q*256 + tid] = review_w_rev[r * RD_N * D_N + q*256 + tid];
    }
    __syncthreads();

    const int e = blockIdx.x * 64 + (tid >> 2);
    const int l = tid & 3;
    if (e >= E_N) return;
    const size_t re = (size_t)r * E_N + e;
    const int row = rows[re];
    const int col = cols[re];

    // ---- cosine sim: each lane one float4 of the 16-vector, quad reduce
    const float4* uh4 = (const float4*)(user_h + ((size_t)r * U_N + row) * D_N);
    const float4* ih4 = (const float4*)(item_h + ((size_t)r * I_N + col) * D_N);
    const float4 a = uh4[l], b = ih4[l];
    float du = dot4(a, a), di = dot4(b, b), dui = dot4(a, b);
    du  += __shfl_xor(du, 1);  du  += __shfl_xor(du, 2);
    di  += __shfl_xor(di, 1);  di  += __shfl_xor(di, 2);
    dui += __shfl_xor(dui, 1); dui += __shfl_xor(dui, 2);
    const float sim_k = dui / sqrtf(du * di) * INV_TAU;

    // ---- sim_all: contiguous mapping — instr q reads one 64B line per quad
    // (k = q, lane l holds float4 l of that k-segment). 4 per-k quad reduces.
    const float4* us4 = (const float4*)(user_hsum + ((size_t)r * U_N + row) * (K_N * D_N));
    const float4* is4 = (const float4*)(item_hsum + ((size_t)r * I_N + col) * (K_N * D_N));
    float p0 = dot4(us4[0*4 + l], is4[0*4 + l]);
    float p1 = dot4(us4[1*4 + l], is4[1*4 + l]);
    float p2 = dot4(us4[2*4 + l], is4[2*4 + l]);
    float p3 = dot4(us4[3*4 + l], is4[3*4 + l]);
    p0 += __shfl_xor(p0, 1); p0 += __shfl_xor(p0, 2);
    p1 += __shfl_xor(p1, 1); p1 += __shfl_xor(p1, 2);
    p2 += __shfl_xor(p2, 1); p2 += __shfl_xor(p2, 2);
    p3 += __shfl_xor(p3, 1); p3 += __shfl_xor(p3, 2);
    const float ssum = expf(p0 * INV_TAU) + expf(p1 * INV_TAU)
                     + expf(p2 * INV_TAU) + expf(p3 * INV_TAU);
    const float exp_sim = expf(sim_k) / ssum;

    // ---- ad: contiguous mapping — iteration it reads one 64B line per quad.
    // k = it/4; per-k partial t0..t3, then 4 quad reduces. The k=KF(=2) chunk
    // float4s are SAVED in sv0..sv3 for Phase B (lane l holds sub-idx 4q+l).
    const float4* rf4 = (const float4*)(review_feat + re * (size_t)(K_N * RD_N));
    const float4* pr4 = (const float4*)proto_s;
    float t0 = 0.f, t1 = 0.f, t2 = 0.f, t3 = 0.f;
#pragma unroll
    for (int it = 0; it < 4; ++it)  t0 += dot4(rf4[it*4 + l], pr4[it*4 + l]);
#pragma unroll
    for (int it = 4; it < 8; ++it)  t1 += dot4(rf4[it*4 + l], pr4[it*4 + l]);
    const float4 sv0 = rf4[32 + l]; t2 += dot4(sv0, pr4[32 + l]);
    const float4 sv1 = rf4[36 + l]; t2 += dot4(sv1, pr4[36 + l]);
    const float4 sv2 = rf4[40 + l]; t2 += dot4(sv2, pr4[40 + l]);
    const float4 sv3 = rf4[44 + l]; t2 += dot4(sv3, pr4[44 + l]);
#pragma unroll
    for (int it = 12; it < 16; ++it) t3 += dot4(rf4[it*4 + l], pr4[it*4 + l]);
    t0 += __shfl_xor(t0, 1); t0 += __shfl_xor(t0, 2);
    t1 += __shfl_xor(t1, 1); t1 += __shfl_xor(t1, 2);
    t2 += __shfl_xor(t2, 1); t2 += __shfl_xor(t2, 2);
    t3 += __shfl_xor(t3, 1); t3 += __shfl_xor(t3, 2);
    const float adsum = expf(t0 * INV_TAU) + expf(t1 * INV_TAU)
                      + expf(t2 * INV_TAU) + expf(t3 * INV_TAU);
    const float ead_rev = expf(t2 * INV_TAU) / adsum;   // k = KF_N = 2

    const float g = 1.0f / (1.0f + expf(-eta[re]));
    const float ead = g * ead_rev + (1.0f - g) * exp_sim;
    if (l == 0) {
        ead_ws[re] = ead;
        atomicAdd(cnt + row, 1);
        atomicAdd(cnt + U_N + col, 1);
        atomicAdd(norm + row, ead);
        atomicAdd(norm + U_N + col, ead);
    }

    // ---- Phase B: unscaled messages, ZERO global loads.
    // lane l owns output columns [4l, 4l+4).
    float4 mf = make_float4(0.f, 0.f, 0.f, 0.f);
    float4 mr = make_float4(0.f, 0.f, 0.f, 0.f);
    const float4* nf4 = (const float4*)nwf_s;
    const float4* nr4 = (const float4*)nwr_s;
    // node part: x_j (j = sl*4+jj) comes from lane sl's cosine registers a,b
#pragma unroll
    for (int sl = 0; sl < 4; ++sl) {
        float4 ub, ib;
        ub.x = __shfl(a.x, sl, 4); ub.y = __shfl(a.y, sl, 4);
        ub.z = __shfl(a.z, sl, 4); ub.w = __shfl(a.w, sl, 4);
        ib.x = __shfl(b.x, sl, 4); ib.y = __shfl(b.y, sl, 4);
        ib.z = __shfl(b.z, sl, 4); ib.w = __shfl(b.w, sl, 4);
#pragma unroll
        for (int jj = 0; jj < 4; ++jj) {
            const int j = sl*4 + jj;
            fma4(mf, comp(ub, jj), nf4[j*4 + l]);
            fma4(mr, comp(ib, jj), nr4[j*4 + l]);
        }
    }
    // review part: rf_k float4 jq (=REG*4+src) lives in lane src, register svREG
    const float4* rf4w = (const float4*)rwf_s;
    const float4* rr4w = (const float4*)rwr_s;
#define REV_BLK(SV, REG)                                                      \
    {                                                                         \
        _Pragma("unroll")                                                     \
        for (int src = 0; src < 4; ++src) {                                   \
            float4 v;                                                         \
            v.x = __shfl(SV.x, src, 4); v.y = __shfl(SV.y, src, 4);           \
            v.z = __shfl(SV.z, src, 4); v.w = __shfl(SV.w, src, 4);           \
            _Pragma("unroll")                                                 \
            for (int jj = 0; jj < 4; ++jj) {                                  \
                const int j = ((REG)*4 + src)*4 + jj;                         \
                fma4(mf, comp(v, jj), rf4w[j*4 + l]);                         \
                fma4(mr, comp(v, jj), rr4w[j*4 + l]);                         \
            }                                                                 \
        }                                                                     \
    }
    REV_BLK(sv0, 0)
    REV_BLK(sv1, 1)
    REV_BLK(sv2, 2)
    REV_BLK(sv3, 3)
#undef REV_BLK

    *((float4*)(m_fwd + re * (size_t)D_N) + l) = mf;   // wave: 1KB contiguous
    *((float4*)(m_rev + re * (size_t)D_N) + l) = mr;
}

// ---------------------------------------------------------------------------
// Segment alloc: replaces the 3-kernel prefix scan. CSR segments only need to
// be DISJOINT, not node-ordered: each block claims a contiguous region via one
// atomicAdd on a global cursor; wave shuffle-scan assigns per-node offsets.
// Consumers use [off[n], off[n]+cnt[n]).
// ---------------------------------------------------------------------------
__global__ __launch_bounds__(256) void alloc_kernel(
    const int* __restrict__ cnt, int* __restrict__ off, int* __restrict__ cursor,
    int* __restrict__ gcnt)
{
    __shared__ int s_wsum[4];
    const int tid = threadIdx.x;
    const int lane = tid & 63;
    const int wid = tid >> 6;
    const int n = blockIdx.x * 256 + tid;
    const int v = (n < NNODE) ? cnt[n] : 0;
    int incl = v;
#pragma unroll
    for (int d = 1; d < 64; d <<= 1) {
        const int x = __shfl_up(incl, d);
        if (lane >= d) incl += x;
    }
    if (lane == 63) s_wsum[wid] = incl;
    __syncthreads();
    if (tid == 0) {
        const int t0 = s_wsum[0], t1 = s_wsum[1], t2 = s_wsum[2], t3 = s_wsum[3];
        const int base = atomicAdd(gcnt, t0 + t1 + t2 + t3);
        s_wsum[0] = base;
        s_wsum[1] = base + t0;
        s_wsum[2] = base + t0 + t1;
        s_wsum[3] = base + t0 + t1 + t2;
    }
    __syncthreads();
    if (n < NNODE) {
        const int o = s_wsum[wid] + incl - v;   // exclusive within wave
        off[n] = o;
        cursor[n] = o;
    }
}

// ---------------------------------------------------------------------------
// Fill + wscale (FUSED): scatter edge ids into CSR list AND write the final
// per-edge weight w = ead/sqrt(norm_u*norm_i) straight into the int_dist
// output region (which doubles as gatherfc's scale array).
// ---------------------------------------------------------------------------
__global__ __launch_bounds__(256) void fillw_kernel(
    const int* __restrict__ rows, const int* __restrict__ cols,
    const float* __restrict__ ead, const float* __restrict__ norm,
    int* __restrict__ cursor, int* __restrict__ list,
    float* __restrict__ w_out)
{
    const int idx = blockIdx.x * 256 + threadIdx.x;
    if (idx >= NE_TOT) return;
    const int row = rows[idx];
    const int col = cols[idx];
    const int p = atomicAdd(cursor + row, 1);
    list[p] = idx;
    const int q = atomicAdd(cursor + U_N + col, 1);
    list[q] = idx;
    w_out[idx] = ead[idx] / sqrtf(norm[row] * norm[U_N + col]);
}

// ---------------------------------------------------------------------------
// Gather + FC (FUSED): 4 lanes per node. Each lane sums one float4 slice of
// w * m over incident edges, applies leaky-ReLU, then the quad broadcasts the
// 16-vector via width-4 shuffles and each lane computes 16 of 64 FC outputs,
// writing to d_out directly. Users consume m_rev; items consume m_fwd.
// Segment = [off[n], off[n]+cnt[n]).
// ---------------------------------------------------------------------------
__global__ __launch_bounds__(256) void gatherfc_kernel(
    const int* __restrict__ off, const int* __restrict__ cnt,
    const int* __restrict__ list,
    const float* __restrict__ m_fwd, const float* __restrict__ m_rev,
    const float* __restrict__ w_edge,
    const float* __restrict__ ufc_w, const float* __restrict__ ufc_b,
    const float* __restrict__ ifc_w, const float* __restrict__ ifc_b,
    float* __restrict__ out)
{
    __shared__ __align__(16) float uw_s[D_N * OUT_N];   // 1024
    __shared__ __align__(16) float iw_s[D_N * OUT_N];   // 1024
    __shared__ __align__(16) float ub_s[OUT_N];
    __shared__ __align__(16) float ib_s[OUT_N];
    const int tid = threadIdx.x;
#pragma unroll
    for (int q = 0; q < 4; ++q) {
        uw_s[q*256 + tid] = ufc_w[q*256 + tid];
        iw_s[q*256 + tid] = ifc_w[q*256 + tid];
    }
    if (tid < OUT_N) ub_s[tid] = ufc_b[tid];
    else if (tid < 2*OUT_N) ib_s[tid - OUT_N] = ifc_b[tid - OUT_N];
    __syncthreads();

    const int gid = blockIdx.x * 256 + tid;
    const int n = gid >> 2;
    const int l = gid & 3;
    if (n >= NNODE) return;
    const int p0 = off[n];
    const int p1 = p0 + cnt[n];
    const bool isU = (n < U_N);
    const float* __restrict__ src = isU ? m_rev : m_fwd;
    float4 acc = make_float4(0.f, 0.f, 0.f, 0.f);
    for (int p = p0; p < p1; ++p) {
        const int e = list[p];
        const float w = w_edge[e];                      // 4B, L2-resident
        const float4 v = *((const float4*)(src + (size_t)e * D_N) + l);
        fma4(acc, w, v);
    }
    // leaky ReLU on this lane's 4 features
    acc.x = (acc.x >= 0.f) ? acc.x : 0.1f * acc.x;
    acc.y = (acc.y >= 0.f) ? acc.y : 0.1f * acc.y;
    acc.z = (acc.z >= 0.f) ? acc.z : 0.1f * acc.z;
    acc.w = (acc.w >= 0.f) ? acc.w : 0.1f * acc.w;

    const float* __restrict__ W = isU ? uw_s : iw_s;
    const float* __restrict__ B = isU ? ub_s : ib_s;
    float* __restrict__ dst = isU ? (out + (size_t)n * OUT_N)
                                  : (out + (size_t)U_N * OUT_N + (size_t)(n - U_N) * OUT_N);

    // lane l computes outputs [16l, 16l+16)
    float4 s0 = *(const float4*)(B + 16*l + 0);
    float4 s1 = *(const float4*)(B + 16*l + 4);
    float4 s2 = *(const float4*)(B + 16*l + 8);
    float4 s3 = *(const float4*)(B + 16*l + 12);
#pragma unroll
    for (int sl = 0; sl < 4; ++sl) {
        float4 fv;
        fv.x = __shfl(acc.x, sl, 4);
        fv.y = __shfl(acc.y, sl, 4);
        fv.z = __shfl(acc.z, sl, 4);
        fv.w = __shfl(acc.w, sl, 4);
#pragma unroll
        for (int jj = 0; jj < 4; ++jj) {
            const int d = sl*4 + jj;
            const float x = comp(fv, jj);
            fma4(s0, x, *(const float4*)(W + d*OUT_N + 16*l + 0));
            fma4(s1, x, *(const float4*)(W + d*OUT_N + 16*l + 4));
            fma4(s2, x, *(const float4*)(W + d*OUT_N + 16*l + 8));
            fma4(s3, x, *(const float4*)(W + d*OUT_N + 16*l + 12));
        }
    }
    ((float4*)dst)[4*l + 0] = s0;
    ((float4*)dst)[4*l + 1] = s1;
    ((float4*)dst)[4*l + 2] = s2;
    ((float4*)dst)[4*l + 3] = s3;
}

// ---------------------------------------------------------------------------
extern "C" void kernel_launch(void* const* d_in, const int* in_sizes, int n_in,
                              void* d_out, int out_size, void* d_ws, size_t ws_size,
                              hipStream_t stream)
{
    const float* user_h       = (const float*)d_in[0];
    const float* item_h       = (const float*)d_in[1];
    const float* user_hsum    = (const float*)d_in[2];
    const float* item_hsum    = (const float*)d_in[3];
    const float* review_feat  = (const float*)d_in[4];
    const float* prototypes   = (const float*)d_in[5];
    const float* eta          = (const float*)d_in[6];
    const float* node_w_fwd   = (const float*)d_in[7];
    const float* node_w_rev   = (const float*)d_in[8];
    const float* review_w_fwd = (const float*)d_in[9];
    const float* review_w_rev = (const float*)d_in[10];
    const float* ufc_w        = (const float*)d_in[11];
    const float* ufc_b        = (const float*)d_in[12];
    const float* ifc_w        = (const float*)d_in[13];
    const float* ifc_b        = (const float*)d_in[14];
    const int*   rows         = (const int*)d_in[15];
    const int*   cols         = (const int*)d_in[16];

    int*   wsi = (int*)d_ws;
    float* wsf = (float*)d_ws;
    float* out = (float*)d_out;

    int*   cnt    = wsi + OFS_CNT;
    float* norm   = wsf + OFS_NORM;
    int*   gcnt   = wsi + OFS_GCNT;
    int*   off    = wsi + OFS_OFF;
    int*   cursor = wsi + OFS_CURSOR;
    int*   list   = wsi + OFS_LIST;
    float* ead    = wsf + OFS_EAD;
    float* m_fwd  = wsf + OFS_MFWD;
    float* m_rev  = wsf + OFS_MREV;

    // zero cnt + norm + gcnt in one shot (contiguous, 300001 ints)
    hipMemsetAsync(wsi, 0, (2 * NNODE + 1) * sizeof(int), stream);

    const dim3 blk(256);
    const dim3 g_e((NE_TOT + 255) / 256);

    phase1_kernel<<<dim3((E_N * 4 + 255) / 256, R_N), blk, 0, stream>>>(
        user_h, item_h, user_hsum, item_hsum, review_feat, prototypes, eta,
        node_w_fwd, node_w_rev, review_w_fwd, review_w_rev,
        rows, cols, ead, m_fwd, m_rev, cnt, norm);

    alloc_kernel<<<dim3(NB_ALLOC), blk, 0, stream>>>(cnt, off, cursor, gcnt);

    float* int_dist_out = out + (size_t)U_N * OUT_N + (size_t)I_N * OUT_N;
    fillw_kernel<<<g_e, blk, 0, stream>>>(rows, cols, ead, norm, cursor, list,
                                          int_dist_out);

    gatherfc_kernel<<<dim3((NNODE * 4 + 255) / 256), blk, 0, stream>>>(
        off, cnt, list, m_fwd, m_rev, int_dist_out,
        ufc_w, ufc_b, ifc_w, ifc_b, out);
}